// Round 9
// baseline (218.429 us; speedup 1.0000x reference)
//
#include <hip/hip_runtime.h>

// LinearAttention: out[b,n,v] = sum_k q[b,k,n] * ktv[b,k,v],
//                  ktv[b,k,v] = sum_n K[b,n,k] * V[b,n,v]
// B=16, DK=64, N=8192, DV=64, fp32.
//
// R9 = R8 (best, 150.0) + fused reduction:
//  - p1_reduce kernel eliminated: last-finishing p1 block per batch b
//    (device-scope atomic counter, threadfence release) reduces the 64
//    partials -> ktv[b] in-kernel, overlapped with other blocks' tails.
//  - counters zeroed via hipMemsetAsync (graph-capture-safe).
//  - p2: q batch 0 issued before the staging barrier.
// Deterministic: reduction always sums c=0..63 in order.

#define B_   16
#define N_   8192
#define DK_  64
#define DV_  64
#define CH_  64      // p1 chunks; 128 rows/block, 32 rows/wave, 2 rounds of 16

// ---------------- Phase 1: partial K^T V + in-kernel reduction ----------------
// grid (64, 16), 256 threads (4 waves). Wave w rows [w*32, w*32+32).
__global__ __launch_bounds__(256) void p1_partial(
    const float* __restrict__ K, const float* __restrict__ V,
    float* __restrict__ part, float* __restrict__ ktv, int* __restrict__ cnt)
{
    __shared__ float sm[4][2048];   // 32 KB; wave w: K rows [0..1023], V rows [1024..2047]
    __shared__ int last;

    const int c = blockIdx.x, b = blockIdx.y, t = threadIdx.x;
    const int w = t >> 6, lane = t & 63;
    const int kk = (lane >> 3) * 8;   // 8 k-groups of 8
    const int vv = (lane & 7) * 8;    // 8 v-groups of 8
    float* Ksw = &sm[w][0];
    float* Vsw = &sm[w][1024];

    const size_t row0 = (size_t)b * N_ + (size_t)c * 128 + (size_t)w * 32;
    const float4* K4 = (const float4*)(K + row0 * DK_);   // 512 float4 (32 rows)
    const float4* V4 = (const float4*)(V + row0 * DV_);

    float acc[8][8] = {};

    #pragma unroll
    for (int r = 0; r < 2; ++r) {
        float4 kb_[4], vb_[4];
        #pragma unroll
        for (int j = 0; j < 4; ++j) kb_[j] = K4[r * 256 + j * 64 + lane];
        #pragma unroll
        for (int j = 0; j < 4; ++j) vb_[j] = V4[r * 256 + j * 64 + lane];
        #pragma unroll
        for (int j = 0; j < 4; ++j) {
            ((float4*)Ksw)[j * 64 + lane] = kb_[j];
            ((float4*)Vsw)[j * 64 + lane] = vb_[j];
        }
        // wave-private: no barrier; compiler lgkmcnt covers ds_write->ds_read
        #pragma unroll 4
        for (int n = 0; n < 16; ++n) {
            alignas(16) float fk[8], fv[8];
            *(float4*)&fk[0] = *(const float4*)&Ksw[n * 64 + kk];
            *(float4*)&fk[4] = *(const float4*)&Ksw[n * 64 + kk + 4];
            *(float4*)&fv[0] = *(const float4*)&Vsw[n * 64 + vv];
            *(float4*)&fv[4] = *(const float4*)&Vsw[n * 64 + vv + 4];
            #pragma unroll
            for (int i = 0; i < 8; ++i)
                #pragma unroll
                for (int j = 0; j < 8; ++j)
                    acc[i][j] += fk[i] * fv[j];
        }
    }

    // staged cross-wave reduce in red[4096] (= sm[0..1] reused).
    __syncthreads();
    float* red = &sm[0][0];
    if (w == 0) {
        #pragma unroll
        for (int i = 0; i < 8; ++i) {
            *(float4*)&red[(kk + i) * 64 + vv]     = make_float4(acc[i][0], acc[i][1], acc[i][2], acc[i][3]);
            *(float4*)&red[(kk + i) * 64 + vv + 4] = make_float4(acc[i][4], acc[i][5], acc[i][6], acc[i][7]);
        }
    }
    __syncthreads();
    #pragma unroll
    for (int ww = 1; ww < 4; ++ww) {
        if (w == ww) {
            #pragma unroll
            for (int i = 0; i < 8; ++i) {
                float4 r0 = *(float4*)&red[(kk + i) * 64 + vv];
                float4 r1 = *(float4*)&red[(kk + i) * 64 + vv + 4];
                r0.x += acc[i][0]; r0.y += acc[i][1]; r0.z += acc[i][2]; r0.w += acc[i][3];
                r1.x += acc[i][4]; r1.y += acc[i][5]; r1.z += acc[i][6]; r1.w += acc[i][7];
                *(float4*)&red[(kk + i) * 64 + vv]     = r0;
                *(float4*)&red[(kk + i) * 64 + vv + 4] = r1;
            }
        }
        __syncthreads();
    }

    float4* P = (float4*)(part + ((size_t)c * B_ + b) * 4096);
    #pragma unroll
    for (int j = 0; j < 4; ++j)
        P[t + 256 * j] = ((const float4*)red)[t + 256 * j];

    // ---- last-block-per-b reduction: partials -> ktv[b] ----
    __syncthreads();                 // all lanes' partial stores drained (vmcnt0)
    if (t == 0) {
        __threadfence();             // device-scope release (L2 writeback)
        last = (atomicAdd(&cnt[b], 1) == CH_ - 1);
    }
    __syncthreads();
    if (last) {
        const float4* Pa = (const float4*)part;
        float4* Kt = (float4*)(ktv + (size_t)b * 4096);
        // 1024 float4 outputs, 4 per thread; c-loop outer for MLP (4 indep loads/iter)
        float4 s0 = {0,0,0,0}, s1 = {0,0,0,0}, s2 = {0,0,0,0}, s3 = {0,0,0,0};
        #pragma unroll 8
        for (int cc = 0; cc < CH_; ++cc) {
            const float4* Pc = Pa + ((size_t)cc * B_ + b) * 1024;
            const float4 a0 = Pc[t], a1 = Pc[t + 256], a2 = Pc[t + 512], a3 = Pc[t + 768];
            s0.x += a0.x; s0.y += a0.y; s0.z += a0.z; s0.w += a0.w;
            s1.x += a1.x; s1.y += a1.y; s1.z += a1.z; s1.w += a1.w;
            s2.x += a2.x; s2.y += a2.y; s2.z += a2.z; s2.w += a2.w;
            s3.x += a3.x; s3.y += a3.y; s3.z += a3.z; s3.w += a3.w;
        }
        Kt[t] = s0; Kt[t + 256] = s1; Kt[t + 512] = s2; Kt[t + 768] = s3;
    }
}

// ---------------- Phase 2: out = q^T ktv ----------------
// grid (64, 16), 256 threads (4 waves). Wave w: 32 n at nb*128+w*32.
// ktv in LDS (reused 128x); q streamed direct in 16-deep float4 batches.
__global__ __launch_bounds__(256) void p2(
    const float* __restrict__ q, const float* __restrict__ ktv,
    float* __restrict__ out)
{
    __shared__ float ks[4096];       // 16 KB: ktv[b], [k][v]

    const int nb = blockIdx.x, b = blockIdx.y, t = threadIdx.x;
    const int w = t >> 6, lane = t & 63;
    const int nl = (lane >> 3) * 4;  // 8 n-groups of 4
    const int vl = (lane & 7) * 8;   // 8 v-groups of 8
    const int n0 = nb * 128 + w * 32;

    const float4* kt4 = (const float4*)(ktv + (size_t)b * 4096);
    #pragma unroll
    for (int j = 0; j < 4; ++j)
        ((float4*)ks)[t + 256 * j] = kt4[t + 256 * j];

    const float* ql = q + (size_t)b * DK_ * N_ + n0 + nl;   // + k*N_

    // q batch 0 in flight before the barrier
    alignas(16) float fq[16][4];
    #pragma unroll
    for (int u = 0; u < 16; ++u)
        *(float4*)&fq[u][0] = *(const float4*)(ql + (size_t)u * N_);

    __syncthreads();

    float acc[4][8] = {};
    #pragma unroll
    for (int kb = 0; kb < 4; ++kb) {
        #pragma unroll
        for (int u = 0; u < 16; ++u) {
            const int k = kb * 16 + u;
            alignas(16) float fv[8];
            *(float4*)&fv[0] = *(const float4*)&ks[k * 64 + vl];
            *(float4*)&fv[4] = *(const float4*)&ks[k * 64 + vl + 4];
            #pragma unroll
            for (int i = 0; i < 4; ++i)
                #pragma unroll
                for (int j = 0; j < 8; ++j)
                    acc[i][j] += fq[u][i] * fv[j];
        }
        if (kb + 1 < 4) {
            #pragma unroll
            for (int u = 0; u < 16; ++u)
                *(float4*)&fq[u][0] =
                    *(const float4*)(ql + (size_t)((kb + 1) * 16 + u) * N_);
        }
    }

    float* ob = out + ((size_t)b * N_ + n0 + nl) * DV_ + vl;
    #pragma unroll
    for (int i = 0; i < 4; ++i) {
        *(float4*)&ob[(size_t)i * DV_]     = make_float4(acc[i][0], acc[i][1], acc[i][2], acc[i][3]);
        *(float4*)&ob[(size_t)i * DV_ + 4] = make_float4(acc[i][4], acc[i][5], acc[i][6], acc[i][7]);
    }
}

extern "C" void kernel_launch(void* const* d_in, const int* in_sizes, int n_in,
                              void* d_out, int out_size, void* d_ws, size_t ws_size,
                              hipStream_t stream)
{
    (void)in_sizes; (void)n_in; (void)out_size; (void)ws_size;
    const float* q = (const float*)d_in[0];   // [16, 64, 8192]
    const float* k = (const float*)d_in[1];   // [16, 8192, 64]
    const float* v = (const float*)d_in[2];   // [16, 8192, 64]
    float* out = (float*)d_out;               // [16, 8192, 64]

    // ws: [64][16][4096] partials (16 MB) + [16][4096] ktv (256 KB) + cnt[16]
    float* part = (float*)d_ws;
    float* ktv  = part + (size_t)CH_ * B_ * 4096;
    int*   cnt  = (int*)(ktv + (size_t)B_ * 4096);

    hipMemsetAsync(cnt, 0, B_ * sizeof(int), stream);
    p1_partial<<<dim3(CH_, B_), 256, 0, stream>>>(k, v, part, ktv, cnt);
    p2<<<dim3(64, B_), 256, 0, stream>>>(q, ktv, out);
}